// Round 6
// baseline (244.830 us; speedup 1.0000x reference)
//
#include <hip/hip_runtime.h>
#include <stdint.h>

// Problem constants
#define B_SZ   1024
#define GF     512
#define GC     63
#define NLEAF  64
#define IN_F   512
#define OUT_F  512

typedef float f32x4 __attribute__((ext_vector_type(4)));
// builtin-facing half types (__fp16: what cvt_pkrtz / mfma_f16 use here)
typedef __fp16 h16x2 __attribute__((ext_vector_type(2)));
typedef __fp16 h16x8 __attribute__((ext_vector_type(8)));
// arithmetic half types (_Float16: native packed math)
typedef _Float16 f16x2 __attribute__((ext_vector_type(2)));

union HF8 { f16x2 h2[4]; h16x8 v; uint4 u; };

__device__ inline f16x2 pkrtz(float a, float b) {
  union { h16x2 r; f16x2 f; } u;
  u.r = __builtin_amdgcn_cvt_pkrtz(a, b);
  return u.f;
}

// ---------------------------------------------------------------------------
// Kernel 1: gatings = sigmoid(x_gating @ gw + gb); leaf_probs tree product.
// (unchanged — proven)
// ---------------------------------------------------------------------------
__global__ __launch_bounds__(512, 2) void k_leafprobs(
    const float* __restrict__ xg, const float* __restrict__ gw,
    const float* __restrict__ gb, float* __restrict__ p_ws)
{
  __shared__ float xsr[GF];
  __shared__ float part[512];
  __shared__ float gates[GC + 1];
  const int b = blockIdx.x;
  const int t = threadIdx.x;

  xsr[t] = xg[(size_t)b * GF + t];
  __syncthreads();

  const int ks = t >> 6, g = t & 63;
  float acc = 0.f;
  if (g < GC) {
    const float* gp = gw + (size_t)(ks * 64) * GC + g;
    const float* xp = &xsr[ks * 64];
#pragma unroll 8
    for (int k = 0; k < 64; ++k) acc += xp[k] * gp[(size_t)k * GC];
  }
  part[t] = acc;
  __syncthreads();

  if (t < GC) {
    float s = gb[t];
#pragma unroll
    for (int r = 0; r < 8; ++r) s += part[r * 64 + t];
    gates[t] = 1.f / (1.f + expf(-s));
  }
  __syncthreads();

  if (t < NLEAF) {
    float v = 1.f;
    int idx = 0, start = 0;
#pragma unroll
    for (int d = 0; d < 6; ++d) {
      int bit = (t >> (5 - d)) & 1;
      float gg = gates[start + idx];
      v *= bit ? (1.f - gg) : gg;
      idx = 2 * idx + bit;
      start += (1 << d);
    }
    p_ws[(size_t)b * NLEAF + t] = v;
  }
}

// ---------------------------------------------------------------------------
// Kernel 2 (FUSED, BARRIER-FREE; R5 + early-clobber asm fix):
// out[b][o] (+)= sum_{i,l} (x[b,i]*p[b,l]) * pw[o][i][l]
// BM=256, BN=64, SK=16, KI=32; 256 thr (4 waves, mi=4).
// R1/R3/R4 evidence: no pipe >27%, occupancy/conflict/latency levers all
// null => the per-phase s_barrier convoy starves the MFMA pipe. Fix: no
// LDS staging of B; each wave loads its OWN fragments global->reg (same
// lane layout as the LDS read delivered), counted vmcnt, zero in-loop
// barriers. 4x L2 traffic for pw (256 MB @34.5 TB/s = 7.4 us) << 16.6 us
// MFMA floor. R5 crash root-cause: asm outputs lacked early-clobber ->
// allocator could alias the dest tuple with the in-flight address pair ->
// async return clobbers a later load's address -> fault. Fixed: "=&v".
// ---------------------------------------------------------------------------
#define SK 16
#define KI 32   // 512 / SK

template <bool ATOMIC>
__global__ __launch_bounds__(256, 2) void k_fused(
    const float* __restrict__ x_leaf,   // [1024][512]
    const float* __restrict__ p_ws,     // [1024][64]
    const float* __restrict__ pw,       // [512][512][64]  ([o][i][l])
    float* __restrict__ dst)            // parts [SK][1024][512] or out
{
  __shared__ __align__(16) float xs[KI][256];   // 32 KB (transposed) — only LDS

  const int tid  = threadIdx.x;
  const int lane = tid & 63;
  const int wid  = tid >> 6;        // 0..3
  const int quad = lane >> 4;
  const int l15  = lane & 15;

  const int bid = blockIdx.x;       // 512
  const int nt  = bid & 7;
  const int mt  = (bid >> 3) & 3;
  const int kc  = bid >> 5;         // 0..15

  const int row_m0 = mt * 256;
  const int o0     = nt * 64;
  const int i0     = kc * KI;
  const int wm     = wid * 64;      // 64 rows per wave

  // ---- stage x slab transposed [KI][256]: one row per thread ----
  {
    const float* src = x_leaf + (size_t)(row_m0 + tid) * IN_F + i0;
#pragma unroll
    for (int q = 0; q < 8; ++q) {
      float4 v = *(const float4*)(src + q * 4);
      xs[q * 4 + 0][tid] = v.x;
      xs[q * 4 + 1][tid] = v.y;
      xs[q * 4 + 2][tid] = v.z;
      xs[q * 4 + 3][tid] = v.w;
    }
  }
  __syncthreads();   // the ONLY barrier (xs visible; drains prologue vmem)

  // ---- p fragments, converted ONCE to f16 (reused all K) ----
  HF8 prh[4][2];
#pragma unroll
  for (int mi = 0; mi < 4; ++mi) {
    const int row = row_m0 + wm + mi * 16 + l15;
#pragma unroll
    for (int ks = 0; ks < 2; ++ks) {
      const f32x4* src = (const f32x4*)(p_ws + (size_t)row * NLEAF + ks * 32 + quad * 8);
      f32x4 lo = src[0], hi = src[1];
      prh[mi][ks].h2[0] = pkrtz(lo[0], lo[1]);
      prh[mi][ks].h2[1] = pkrtz(lo[2], lo[3]);
      prh[mi][ks].h2[2] = pkrtz(hi[0], hi[1]);
      prh[mi][ks].h2[3] = pkrtz(hi[2], hi[3]);
    }
  }

  // ---- per-lane B pointers: lane reads row (o0+ni*16+l15), col quad*8 ----
  // fragment (ks,ni) = 8 f32 at +ks*128B; per i-step advance = 64 fl = 256B.
  const float* p0 = pw + (((size_t)(o0 + l15) * IN_F + i0) * NLEAF + quad * 8);
  const float* p1 = p0 + (size_t)16 * IN_F * NLEAF;
  const float* p2 = p0 + (size_t)32 * IN_F * NLEAF;
  const float* p3 = p0 + (size_t)48 * IN_F * NLEAF;

  f32x4 acc[4][4];
#pragma unroll
  for (int mi = 0; mi < 4; ++mi)
#pragma unroll
    for (int ni = 0; ni < 4; ++ni)
      acc[mi][ni] = (f32x4)(0.f);

  f32x4 raw0[4], raw1[4], raw2[4], raw3[4];  // 64 VGPR: 1 B-tile in flight
  HF8 fr[2][4];                              // current tile's f16 fragments

  // issue 4 loads for one ni-group: ks0 (0,+16B) and ks1 (+128B,+144B).
  // volatile + "memory": never sinks. "=&v" EARLY-CLOBBER is required:
  // without it the allocator may alias a dest tuple with the address pair,
  // and an early async return clobbers a later load's address (R5 fault).
#define BLOADN(PN, RAW)                                                       \
  asm volatile(                                                               \
      "global_load_dwordx4 %0, %4, off\n\t"                                   \
      "global_load_dwordx4 %1, %4, off offset:16\n\t"                         \
      "global_load_dwordx4 %2, %4, off offset:128\n\t"                        \
      "global_load_dwordx4 %3, %4, off offset:144"                            \
      : "=&v"(RAW[0]), "=&v"(RAW[1]), "=&v"(RAW[2]), "=&v"(RAW[3])            \
      : "v"(PN) : "memory");

  // counted wait tied to RAW so consumers can't hoist; sched_barrier per
  // rule 18 (compiler may otherwise lift dependent VALU past the waitcnt).
#define BWAITR(RAW, N)                                                        \
  asm volatile("s_waitcnt vmcnt(" #N ")"                                      \
               : "+v"(RAW[0]), "+v"(RAW[1]), "+v"(RAW[2]), "+v"(RAW[3])       \
               ::"memory");                                                   \
  __builtin_amdgcn_sched_barrier(0);

#define CVTN(RAW, NI)                                                         \
  {                                                                           \
    fr[0][NI].h2[0] = pkrtz(RAW[0][0], RAW[0][1]);                            \
    fr[0][NI].h2[1] = pkrtz(RAW[0][2], RAW[0][3]);                            \
    fr[0][NI].h2[2] = pkrtz(RAW[1][0], RAW[1][1]);                            \
    fr[0][NI].h2[3] = pkrtz(RAW[1][2], RAW[1][3]);                            \
    fr[1][NI].h2[0] = pkrtz(RAW[2][0], RAW[2][1]);                            \
    fr[1][NI].h2[1] = pkrtz(RAW[2][2], RAW[2][3]);                            \
    fr[1][NI].h2[2] = pkrtz(RAW[3][0], RAW[3][1]);                            \
    fr[1][NI].h2[3] = pkrtz(RAW[3][2], RAW[3][3]);                            \
  }

  // 16 loads; ours are the NEWEST vmem ops and vmcnt retire is FIFO, so
  // counted waits stay conservative even if older compiler loads linger.
#define BLOADALL()                                                            \
  {                                                                           \
    BLOADN(p0, raw0) BLOADN(p1, raw1) BLOADN(p2, raw2) BLOADN(p3, raw3)       \
    p0 += NLEAF; p1 += NLEAF; p2 += NLEAF; p3 += NLEAF;                       \
  }

  // convert the in-flight tile: waits 12/8/4/0 in issue order.
#define CVTALL()                                                              \
  {                                                                           \
    BWAITR(raw0, 12) CVTN(raw0, 0)                                            \
    BWAITR(raw1, 8)  CVTN(raw1, 1)                                            \
    BWAITR(raw2, 4)  CVTN(raw2, 2)                                            \
    BWAITR(raw3, 0)  CVTN(raw3, 3)                                            \
  }

#define COMPUTE(IT)                                                           \
  {                                                                           \
    float xvf[4];                                                             \
    _Float16 xh[4];                                                           \
    _Pragma("unroll")                                                         \
    for (int mi = 0; mi < 4; ++mi) xvf[mi] = xs[(IT)][wm + mi * 16 + l15];    \
    _Pragma("unroll")                                                         \
    for (int mi = 0; mi < 4; ++mi) xh[mi] = (_Float16)xvf[mi];                \
    __builtin_amdgcn_s_setprio(1);                                            \
    _Pragma("unroll")                                                         \
    for (int ks = 0; ks < 2; ++ks) {                                          \
      h16x8 af[4];                                                            \
      _Pragma("unroll")                                                       \
      for (int mi = 0; mi < 4; ++mi) {                                        \
        HF8 t_;                                                               \
        f16x2 xp_; xp_[0] = xh[mi]; xp_[1] = xh[mi];                          \
        _Pragma("unroll")                                                     \
        for (int j = 0; j < 4; ++j) t_.h2[j] = prh[mi][ks].h2[j] * xp_;       \
        af[mi] = t_.v;                                                        \
      }                                                                       \
      _Pragma("unroll")                                                       \
      for (int ni = 0; ni < 4; ++ni) {                                        \
        _Pragma("unroll")                                                     \
        for (int mi = 0; mi < 4; ++mi)                                        \
          acc[mi][ni] = __builtin_amdgcn_mfma_f32_16x16x32_f16(               \
              af[mi], fr[ks][ni].v, acc[mi][ni], 0, 0, 0);                    \
      }                                                                       \
    }                                                                         \
    __builtin_amdgcn_s_setprio(0);                                            \
  }

  // ---- pipeline: fr = tile0; tile1 in flight ----
  BLOADALL()        // tile 0
  CVTALL()          // fr <- tile 0
  BLOADALL()        // tile 1 issued

  for (int it = 0; it < KI - 2; ++it) {
    COMPUTE(it)     // uses fr (tile it); WAR keeps CVT below MFMA reads
    CVTALL()        // fr <- tile it+1 (in flight since last iter)
    BLOADALL()      // issue tile it+2
  }
  COMPUTE(KI - 2)
  CVTALL()          // fr <- tile 31
  COMPUTE(KI - 1)

#undef BLOADN
#undef BWAITR
#undef CVTN
#undef BLOADALL
#undef CVTALL
#undef COMPUTE

  // ---- epilogue ----
#pragma unroll
  for (int mi = 0; mi < 4; ++mi) {
#pragma unroll
    for (int ni = 0; ni < 4; ++ni) {
      int row = row_m0 + wm + mi * 16 + quad * 4;
      int col = o0 + ni * 16 + l15;
      if (ATOMIC) {
        float* o = dst + (size_t)row * OUT_F + col;
        atomicAdd(o,             acc[mi][ni][0]);
        atomicAdd(o + OUT_F,     acc[mi][ni][1]);
        atomicAdd(o + 2 * OUT_F, acc[mi][ni][2]);
        atomicAdd(o + 3 * OUT_F, acc[mi][ni][3]);
      } else {
        float* o = dst + ((size_t)kc << 19) + (size_t)row * OUT_F + col;
        o[0]         = acc[mi][ni][0];
        o[OUT_F]     = acc[mi][ni][1];
        o[2 * OUT_F] = acc[mi][ni][2];
        o[3 * OUT_F] = acc[mi][ni][3];
      }
    }
  }
}

// ---------------------------------------------------------------------------
// Kernel 3: out[b][o] = sum_kc parts[kc][b][o] + sum_l p[b][l]*pb[o][l]
// (unchanged; nparts==0 -> bias-only init for atomic fallback)
// ---------------------------------------------------------------------------
__global__ __launch_bounds__(256, 4) void k_reduce(
    const float* __restrict__ parts, const float* __restrict__ p_ws,
    const float* __restrict__ pb, float* __restrict__ out, int nparts)
{
  __shared__ float ps_l[2 * NLEAF];
  const int t  = threadIdx.x;
  const int b0 = blockIdx.x * 2;

  if (t < 32)
    ((f32x4*)ps_l)[t] = ((const f32x4*)(p_ws + (size_t)b0 * NLEAF))[t];
  __syncthreads();

  const int row = b0 + (t >> 7);
  const int c0  = (t & 127) * 4;
  const f32x4* ps = (const f32x4*)&ps_l[(t >> 7) * NLEAF];

  f32x4 a;
#pragma unroll
  for (int jo = 0; jo < 4; ++jo) {
    const f32x4* pbo = (const f32x4*)(pb + (size_t)(c0 + jo) * NLEAF);
    f32x4 s = (f32x4)(0.f);
#pragma unroll
    for (int lv = 0; lv < 16; ++lv) s += pbo[lv] * ps[lv];
    a[jo] = s[0] + s[1] + s[2] + s[3];
  }

#pragma unroll 8
  for (int k = 0; k < nparts; ++k)
    a += *(const f32x4*)(parts + ((size_t)k << 19) + (size_t)row * OUT_F + c0);

  *(f32x4*)(out + (size_t)row * OUT_F + c0) = a;
}

// ---------------------------------------------------------------------------
extern "C" void kernel_launch(void* const* d_in, const int* in_sizes, int n_in,
                              void* d_out, int out_size, void* d_ws, size_t ws_size,
                              hipStream_t stream) {
  const float* xg = (const float*)d_in[0];   // x_gating [1024][512]
  const float* xl = (const float*)d_in[1];   // x_leaf   [1024][512]
  const float* gw = (const float*)d_in[2];   // [512][63]
  const float* gb = (const float*)d_in[3];   // [63]
  const float* pw = (const float*)d_in[4];   // [512][512][64]
  const float* pb = (const float*)d_in[5];   // [512][64]
  float* out = (float*)d_out;

  // ws: p fp32 (256 KB) | parts fp32 [SK][1024][512] (32 MB)
  const size_t P_BYTES = (size_t)B_SZ * NLEAF * 4;
  const size_t SLICE   = (size_t)B_SZ * OUT_F * 4;

  float* p_ws  = (float*)d_ws;
  float* parts = (float*)((char*)d_ws + P_BYTES);

  k_leafprobs<<<dim3(B_SZ), dim3(512), 0, stream>>>(xg, gw, gb, p_ws);

  if (ws_size >= P_BYTES + SK * SLICE) {
    k_fused<false><<<dim3(512), dim3(256), 0, stream>>>(xl, p_ws, pw, parts);
    k_reduce<<<dim3(512), dim3(256), 0, stream>>>(parts, p_ws, pb, out, SK);
  } else {
    k_reduce<<<dim3(512), dim3(256), 0, stream>>>(parts, p_ws, pb, out, 0);
    k_fused<true><<<dim3(512), dim3(256), 0, stream>>>(xl, p_ws, pw, out);
  }
}

// Round 7
// 166.467 us; speedup vs baseline: 1.4707x; 1.4707x over previous
//
#include <hip/hip_runtime.h>
#include <stdint.h>

// Problem constants
#define B_SZ   1024
#define GF     512
#define GC     63
#define NLEAF  64
#define IN_F   512
#define OUT_F  512

typedef float f32x4 __attribute__((ext_vector_type(4)));
// builtin-facing half types (__fp16: what cvt_pkrtz / mfma_f16 use here)
typedef __fp16 h16x2 __attribute__((ext_vector_type(2)));
typedef __fp16 h16x8 __attribute__((ext_vector_type(8)));
// arithmetic half types (_Float16: native packed math)
typedef _Float16 f16x2 __attribute__((ext_vector_type(2)));

union HF8 { f16x2 h2[4]; h16x8 v; uint4 u; };

__device__ inline f16x2 pkrtz(float a, float b) {
  union { h16x2 r; f16x2 f; } u;
  u.r = __builtin_amdgcn_cvt_pkrtz(a, b);
  return u.f;
}

// ---------------------------------------------------------------------------
// Kernel 1: gatings = sigmoid(x_gating @ gw + gb); leaf_probs tree product.
// (unchanged — proven)
// ---------------------------------------------------------------------------
__global__ __launch_bounds__(512, 2) void k_leafprobs(
    const float* __restrict__ xg, const float* __restrict__ gw,
    const float* __restrict__ gb, float* __restrict__ p_ws)
{
  __shared__ float xsr[GF];
  __shared__ float part[512];
  __shared__ float gates[GC + 1];
  const int b = blockIdx.x;
  const int t = threadIdx.x;

  xsr[t] = xg[(size_t)b * GF + t];
  __syncthreads();

  const int ks = t >> 6, g = t & 63;
  float acc = 0.f;
  if (g < GC) {
    const float* gp = gw + (size_t)(ks * 64) * GC + g;
    const float* xp = &xsr[ks * 64];
#pragma unroll 8
    for (int k = 0; k < 64; ++k) acc += xp[k] * gp[(size_t)k * GC];
  }
  part[t] = acc;
  __syncthreads();

  if (t < GC) {
    float s = gb[t];
#pragma unroll
    for (int r = 0; r < 8; ++r) s += part[r * 64 + t];
    gates[t] = 1.f / (1.f + expf(-s));
  }
  __syncthreads();

  if (t < NLEAF) {
    float v = 1.f;
    int idx = 0, start = 0;
#pragma unroll
    for (int d = 0; d < 6; ++d) {
      int bit = (t >> (5 - d)) & 1;
      float gg = gates[start + idx];
      v *= bit ? (1.f - gg) : gg;
      idx = 2 * idx + bit;
      start += (1 << d);
    }
    p_ws[(size_t)b * NLEAF + t] = v;
  }
}

// ---------------------------------------------------------------------------
// Kernel 2 (FUSED, R4 structure + 2-tiles-per-phase):
// R6 disproved the barrier-convoy theory (barrier-free = 2.7x WORSE) and
// showed occupancy can't rise (unified reg use ~170 incl AGPR acc).
// R0/R1/R3/R4 all sit at the 2-barrier-structure ceiling (36% of the 17.6us
// f16 MFMA floor): per phase ~1240 cyc MFMA + ~2400 cyc FIXED overhead
// (lgkm drain + barrier skew + stage wait). This version amortizes the
// fixed cost: 16 phases x 2 i-steps each; the stage of the NEXT pair is
// placed BETWEEN the two COMPUTE halves (hidden under MFMA); prefetch
// lookahead = 2 full phases >> HBM latency. vmcnt ledger:
//   steady phase p: enter with tiles {2p+2..2p+5} in flight (16 loads);
//   mid: wait 2p+2 (vmcnt12) stage -> load 2p+6; end: wait 2p+3 (vmcnt12)
//   stage -> load 2p+7. Drain: p13 12/8, p14 4/0, p15 compute-only.
// ---------------------------------------------------------------------------
#define SK 16
#define KI 32   // 512 / SK

template <bool ATOMIC>
__global__ __launch_bounds__(256, 2) void k_fused(
    const float* __restrict__ x_leaf,   // [1024][512]
    const float* __restrict__ p_ws,     // [1024][64]
    const float* __restrict__ pw,       // [512][512][64]  ([o][i][l])
    float* __restrict__ dst)            // parts [SK][1024][512] or out
{
  __shared__ __align__(16) float         xs[KI][256];    // 32 KB (transposed)
  __shared__ __align__(16) unsigned char bs8[2 * 16384]; // 2buf x 2sub x 8KB

  const int tid  = threadIdx.x;
  const int lane = tid & 63;
  const int wid  = tid >> 6;        // 0..3
  const int quad = lane >> 4;
  const int l15  = lane & 15;
  const int l7   = l15 & 7;

  const int bid = blockIdx.x;       // 512
  const int nt  = bid & 7;
  const int mt  = (bid >> 3) & 3;
  const int kc  = bid >> 5;         // 0..15

  const int row_m0 = mt * 256;
  const int o0     = nt * 64;
  const int i0     = kc * KI;
  const int wm     = wid * 64;      // 64 rows per wave

  // ---- stage x slab transposed [KI][256]: one row per thread ----
  {
    const float* src = x_leaf + (size_t)(row_m0 + tid) * IN_F + i0;
#pragma unroll
    for (int q = 0; q < 8; ++q) {
      float4 v = *(const float4*)(src + q * 4);
      xs[q * 4 + 0][tid] = v.x;
      xs[q * 4 + 1][tid] = v.y;
      xs[q * 4 + 2][tid] = v.z;
      xs[q * 4 + 3][tid] = v.w;
    }
  }

  // ---- p fragments, converted ONCE to f16 (reused all K) ----
  HF8 prh[4][2];
#pragma unroll
  for (int mi = 0; mi < 4; ++mi) {
    const int row = row_m0 + wm + mi * 16 + l15;
#pragma unroll
    for (int ks = 0; ks < 2; ++ks) {
      const f32x4* src = (const f32x4*)(p_ws + (size_t)row * NLEAF + ks * 32 + quad * 8);
      f32x4 lo = src[0], hi = src[1];
      prh[mi][ks].h2[0] = pkrtz(lo[0], lo[1]);
      prh[mi][ks].h2[1] = pkrtz(lo[2], lo[3]);
      prh[mi][ks].h2[2] = pkrtz(hi[0], hi[1]);
      prh[mi][ks].h2[3] = pkrtz(hi[2], hi[3]);
    }
  }

  // ---- B-load geometry: thread = (br = tid>>2 of 64 o-rows, seg = tid&3) ----
  const int br  = tid >> 2;
  const int seg = tid & 3;
  const float* bsrc0 = pw + ((size_t)(o0 + br) * IN_F + i0) * NLEAF + seg * 16;

  // swizzled LDS offsets (XOR touches byte bits 4-6 only; fields don't carry)
  const int wsw   = (br & 7) << 4;
  const int woff0 = br * 128 + ((seg * 32) ^ wsw);
  const int woff1 = br * 128 + ((seg * 32 + 16) ^ wsw);
  int coff[2];
#pragma unroll
  for (int ks = 0; ks < 2; ++ks)
    coff[ks] = (ks * 64 + quad * 16) ^ (l7 << 4);
  const int rbase = l15 * 128;

  f32x4 acc[4][4];
#pragma unroll
  for (int mi = 0; mi < 4; ++mi)
#pragma unroll
    for (int ni = 0; ni < 4; ++ni)
      acc[mi][ni] = (f32x4)(0.f);

  f32x4 rb[4][4];   // 4-slot register prefetch (tile T -> slot T&3)

  // volatile asm loads: issue exactly here, never sink; "=&v" early-clobber
  // (R5 lesson: without it a dest tuple may alias the in-flight addr pair).
#define BLOAD(T, SLOT)                                                        \
  {                                                                           \
    const float* a_ = bsrc0 + (size_t)(T) * NLEAF;                            \
    asm volatile(                                                             \
        "global_load_dwordx4 %0, %4, off\n\t"                                 \
        "global_load_dwordx4 %1, %4, off offset:16\n\t"                       \
        "global_load_dwordx4 %2, %4, off offset:32\n\t"                       \
        "global_load_dwordx4 %3, %4, off offset:48"                           \
        : "=&v"(rb[SLOT][0]), "=&v"(rb[SLOT][1]),                             \
          "=&v"(rb[SLOT][2]), "=&v"(rb[SLOT][3])                              \
        : "v"(a_) : "memory");                                                \
  }

  // counted wait tied to the slot's regs; sched_barrier per rule 18.
#define BWAIT_(SLOT, N)                                                       \
  asm volatile("s_waitcnt vmcnt(" #N ")"                                      \
               : "+v"(rb[SLOT][0]), "+v"(rb[SLOT][1]),                        \
                 "+v"(rb[SLOT][2]), "+v"(rb[SLOT][3])::"memory");             \
  __builtin_amdgcn_sched_barrier(0);
#define BWAIT(SLOT, N) BWAIT_(SLOT, N)

#define BSTAGE(SLOT, BUF, SUB)                                                \
  {                                                                           \
    HF8 c0_, c1_;                                                             \
    f32x4 a0_ = rb[SLOT][0], a1_ = rb[SLOT][1];                               \
    f32x4 a2_ = rb[SLOT][2], a3_ = rb[SLOT][3];                               \
    c0_.h2[0] = pkrtz(a0_[0], a0_[1]);                                        \
    c0_.h2[1] = pkrtz(a0_[2], a0_[3]);                                        \
    c0_.h2[2] = pkrtz(a1_[0], a1_[1]);                                        \
    c0_.h2[3] = pkrtz(a1_[2], a1_[3]);                                        \
    c1_.h2[0] = pkrtz(a2_[0], a2_[1]);                                        \
    c1_.h2[1] = pkrtz(a2_[2], a2_[3]);                                        \
    c1_.h2[2] = pkrtz(a3_[0], a3_[1]);                                        \
    c1_.h2[3] = pkrtz(a3_[2], a3_[3]);                                        \
    unsigned char* d_ = bs8 + (BUF) * 16384 + (SUB) * 8192;                   \
    *(uint4*)(d_ + woff0) = c0_.u;                                            \
    *(uint4*)(d_ + woff1) = c1_.u;                                            \
  }

  // own DS ops drained, then workgroup barrier — NO vmcnt drain: the pinned
  // global B-prefetch stays in flight across barriers.
#define BARRIER() asm volatile("s_waitcnt lgkmcnt(0)\n\ts_barrier" ::: "memory")

#define COMPUTE(IT, BUF, SUB)                                                 \
  {                                                                           \
    float xvf[4];                                                             \
    _Float16 xh[4];                                                           \
    _Pragma("unroll")                                                         \
    for (int mi = 0; mi < 4; ++mi) xvf[mi] = xs[(IT)][wm + mi * 16 + l15];    \
    _Pragma("unroll")                                                         \
    for (int mi = 0; mi < 4; ++mi) xh[mi] = (_Float16)xvf[mi];                \
    const unsigned char* bsr_ = bs8 + (BUF) * 16384 + (SUB) * 8192;           \
    __builtin_amdgcn_s_setprio(1);                                            \
    _Pragma("unroll")                                                         \
    for (int ks = 0; ks < 2; ++ks) {                                          \
      h16x8 af[4];                                                            \
      _Pragma("unroll")                                                       \
      for (int mi = 0; mi < 4; ++mi) {                                        \
        HF8 t_;                                                               \
        f16x2 xp_; xp_[0] = xh[mi]; xp_[1] = xh[mi];                          \
        _Pragma("unroll")                                                     \
        for (int j = 0; j < 4; ++j) t_.h2[j] = prh[mi][ks].h2[j] * xp_;       \
        af[mi] = t_.v;                                                        \
      }                                                                       \
      _Pragma("unroll")                                                       \
      for (int ni = 0; ni < 4; ++ni) {                                        \
        h16x8 bfr = *(const h16x8*)(bsr_ + ni * 2048 + rbase + coff[ks]);     \
        _Pragma("unroll")                                                     \
        for (int mi = 0; mi < 4; ++mi)                                        \
          acc[mi][ni] = __builtin_amdgcn_mfma_f32_16x16x32_f16(               \
              af[mi], bfr, acc[mi][ni], 0, 0, 0);                             \
      }                                                                       \
    }                                                                         \
    __builtin_amdgcn_s_setprio(0);                                            \
  }

// Phase: compute tiles IT0,IT0+1 from bs[BUF]; stage IT0+2,IT0+3 into
// bs[BUF^1] split across the two compute halves; optionally load IT0+6/7.
#define PHASE(IT0, BUF, SA, SB, WA, WB, DLA, DLB)                             \
  {                                                                           \
    COMPUTE(IT0, BUF, 0)                                                      \
    BWAIT(SA, WA)                                                             \
    BSTAGE(SA, (BUF) ^ 1, 0)                                                  \
    if (DLA) { BLOAD((IT0) + 6, SA) }                                         \
    COMPUTE((IT0) + 1, BUF, 1)                                                \
    BWAIT(SB, WB)                                                             \
    BSTAGE(SB, (BUF) ^ 1, 1)                                                  \
    if (DLB) { BLOAD((IT0) + 7, SB) }                                         \
    BARRIER();                                                                \
  }

  // ---- prologue: tiles 0..3 issued; stage 0,1; issue 4,5 ----
  BLOAD(0, 0)
  BLOAD(1, 1)
  BLOAD(2, 2)
  BLOAD(3, 3)
  BWAIT(0, 12)
  BSTAGE(0, 0, 0)
  BWAIT(1, 8)
  BSTAGE(1, 0, 1)
  BLOAD(4, 0)
  BLOAD(5, 1)
  BARRIER();         // xs + bs[0] visible; tiles {2,3,4,5} in flight

  // ---- steady phases p=0..12 (tiles 0..25; loads through tile 31) ----
  for (int pp = 0; pp < 24; pp += 8) {
    PHASE(pp + 0, 0, 2, 3, 12, 12, 1, 1)
    PHASE(pp + 2, 1, 0, 1, 12, 12, 1, 1)
    PHASE(pp + 4, 0, 2, 3, 12, 12, 1, 1)
    PHASE(pp + 6, 1, 0, 1, 12, 12, 1, 1)
  }
  PHASE(24, 0, 2, 3, 12, 12, 1, 1)   // p12: loads tiles 30,31
  // ---- drain ----
  PHASE(26, 1, 0, 1, 12, 8, 0, 0)    // p13: stage 28,29
  PHASE(28, 0, 2, 3, 4, 0, 0, 0)     // p14: stage 30,31
  COMPUTE(30, 1, 0)                  // p15: compute-only
  COMPUTE(31, 1, 1)

#undef BLOAD
#undef BWAIT
#undef BWAIT_
#undef BSTAGE
#undef BARRIER
#undef COMPUTE
#undef PHASE

  // ---- epilogue ----
#pragma unroll
  for (int mi = 0; mi < 4; ++mi) {
#pragma unroll
    for (int ni = 0; ni < 4; ++ni) {
      int row = row_m0 + wm + mi * 16 + quad * 4;
      int col = o0 + ni * 16 + l15;
      if (ATOMIC) {
        float* o = dst + (size_t)row * OUT_F + col;
        atomicAdd(o,             acc[mi][ni][0]);
        atomicAdd(o + OUT_F,     acc[mi][ni][1]);
        atomicAdd(o + 2 * OUT_F, acc[mi][ni][2]);
        atomicAdd(o + 3 * OUT_F, acc[mi][ni][3]);
      } else {
        float* o = dst + ((size_t)kc << 19) + (size_t)row * OUT_F + col;
        o[0]         = acc[mi][ni][0];
        o[OUT_F]     = acc[mi][ni][1];
        o[2 * OUT_F] = acc[mi][ni][2];
        o[3 * OUT_F] = acc[mi][ni][3];
      }
    }
  }
}

// ---------------------------------------------------------------------------
// Kernel 3: out[b][o] = sum_kc parts[kc][b][o] + sum_l p[b][l]*pb[o][l]
// (unchanged; nparts==0 -> bias-only init for atomic fallback)
// ---------------------------------------------------------------------------
__global__ __launch_bounds__(256, 4) void k_reduce(
    const float* __restrict__ parts, const float* __restrict__ p_ws,
    const float* __restrict__ pb, float* __restrict__ out, int nparts)
{
  __shared__ float ps_l[2 * NLEAF];
  const int t  = threadIdx.x;
  const int b0 = blockIdx.x * 2;

  if (t < 32)
    ((f32x4*)ps_l)[t] = ((const f32x4*)(p_ws + (size_t)b0 * NLEAF))[t];
  __syncthreads();

  const int row = b0 + (t >> 7);
  const int c0  = (t & 127) * 4;
  const f32x4* ps = (const f32x4*)&ps_l[(t >> 7) * NLEAF];

  f32x4 a;
#pragma unroll
  for (int jo = 0; jo < 4; ++jo) {
    const f32x4* pbo = (const f32x4*)(pb + (size_t)(c0 + jo) * NLEAF);
    f32x4 s = (f32x4)(0.f);
#pragma unroll
    for (int lv = 0; lv < 16; ++lv) s += pbo[lv] * ps[lv];
    a[jo] = s[0] + s[1] + s[2] + s[3];
  }

#pragma unroll 8
  for (int k = 0; k < nparts; ++k)
    a += *(const f32x4*)(parts + ((size_t)k << 19) + (size_t)row * OUT_F + c0);

  *(f32x4*)(out + (size_t)row * OUT_F + c0) = a;
}

// ---------------------------------------------------------------------------
extern "C" void kernel_launch(void* const* d_in, const int* in_sizes, int n_in,
                              void* d_out, int out_size, void* d_ws, size_t ws_size,
                              hipStream_t stream) {
  const float* xg = (const float*)d_in[0];   // x_gating [1024][512]
  const float* xl = (const float*)d_in[1];   // x_leaf   [1024][512]
  const float* gw = (const float*)d_in[2];   // [512][63]
  const float* gb = (const float*)d_in[3];   // [63]
  const float* pw = (const float*)d_in[4];   // [512][512][64]
  const float* pb = (const float*)d_in[5];   // [512][64]
  float* out = (float*)d_out;

  // ws: p fp32 (256 KB) | parts fp32 [SK][1024][512] (32 MB)
  const size_t P_BYTES = (size_t)B_SZ * NLEAF * 4;
  const size_t SLICE   = (size_t)B_SZ * OUT_F * 4;

  float* p_ws  = (float*)d_ws;
  float* parts = (float*)((char*)d_ws + P_BYTES);

  k_leafprobs<<<dim3(B_SZ), dim3(512), 0, stream>>>(xg, gw, gb, p_ws);

  if (ws_size >= P_BYTES + SK * SLICE) {
    k_fused<false><<<dim3(512), dim3(256), 0, stream>>>(xl, p_ws, pw, parts);
    k_reduce<<<dim3(512), dim3(256), 0, stream>>>(parts, p_ws, pb, out, SK);
  } else {
    k_reduce<<<dim3(512), dim3(256), 0, stream>>>(parts, p_ws, pb, out, 0);
    k_fused<true><<<dim3(512), dim3(256), 0, stream>>>(xl, p_ws, pw, out);
  }
}

// Round 8
// 146.363 us; speedup vs baseline: 1.6728x; 1.1374x over previous
//
#include <hip/hip_runtime.h>
#include <stdint.h>

// Problem constants
#define B_SZ   1024
#define GF     512
#define GC     63
#define NLEAF  64
#define IN_F   512
#define OUT_F  512

typedef float f32x4 __attribute__((ext_vector_type(4)));
// builtin-facing half types (__fp16: what cvt_pkrtz / mfma_f16 use here)
typedef __fp16 h16x2 __attribute__((ext_vector_type(2)));
typedef __fp16 h16x8 __attribute__((ext_vector_type(8)));
// arithmetic half types (_Float16: native packed math)
typedef _Float16 f16x2 __attribute__((ext_vector_type(2)));

union HF8 { f16x2 h2[4]; h16x8 v; uint4 u; };

__device__ inline f16x2 pkrtz(float a, float b) {
  union { h16x2 r; f16x2 f; } u;
  u.r = __builtin_amdgcn_cvt_pkrtz(a, b);
  return u.f;
}

// ---------------------------------------------------------------------------
// Kernel 1: gatings = sigmoid(x_gating @ gw + gb); leaf_probs tree product.
// (unchanged — proven)
// ---------------------------------------------------------------------------
__global__ __launch_bounds__(512, 2) void k_leafprobs(
    const float* __restrict__ xg, const float* __restrict__ gw,
    const float* __restrict__ gb, float* __restrict__ p_ws)
{
  __shared__ float xsr[GF];
  __shared__ float part[512];
  __shared__ float gates[GC + 1];
  const int b = blockIdx.x;
  const int t = threadIdx.x;

  xsr[t] = xg[(size_t)b * GF + t];
  __syncthreads();

  const int ks = t >> 6, g = t & 63;
  float acc = 0.f;
  if (g < GC) {
    const float* gp = gw + (size_t)(ks * 64) * GC + g;
    const float* xp = &xsr[ks * 64];
#pragma unroll 8
    for (int k = 0; k < 64; ++k) acc += xp[k] * gp[(size_t)k * GC];
  }
  part[t] = acc;
  __syncthreads();

  if (t < GC) {
    float s = gb[t];
#pragma unroll
    for (int r = 0; r < 8; ++r) s += part[r * 64 + t];
    gates[t] = 1.f / (1.f + expf(-s));
  }
  __syncthreads();

  if (t < NLEAF) {
    float v = 1.f;
    int idx = 0, start = 0;
#pragma unroll
    for (int d = 0; d < 6; ++d) {
      int bit = (t >> (5 - d)) & 1;
      float gg = gates[start + idx];
      v *= bit ? (1.f - gg) : gg;
      idx = 2 * idx + bit;
      start += (1 << d);
    }
    p_ws[(size_t)b * NLEAF + t] = v;
  }
}

// ---------------------------------------------------------------------------
// Kernel 2 (FUSED): R7 skeleton + 3 changes:
//  (1) A-build pipelined ONE i-step ahead (afA/afB ping-pong, static names):
//      PREP(t+1) issues before MFMA(t); PREP reads only xs/prh (never bs),
//      so it's barrier-independent. Hides the ~200cyc/i-step serial prelude
//      (xs ds_read latency + 32 pk_mul) that sat between barrier and MFMAs.
//  (2) sched_barrier(0) REMOVED from BWAIT: rb consumers have true SSA deps
//      via the "+v" ties (rule-18's hazard was dep-less MFMA vs ds_read),
//      so the fence only blocked stage/MFMA interleaving.
//  (3) pb term folded in (kc==0): one extra pseudo-i-step with A=prh (x==1),
//      B=pb staged like a pw tile. k_reduce loses its pb GEMV entirely.
// vmcnt ledger identical to R7 (steady 12/12; drain 12/8 then 4/0).
// ---------------------------------------------------------------------------
#define SK 16
#define KI 32   // 512 / SK

template <bool ATOMIC>
__global__ __launch_bounds__(256, 2) void k_fused(
    const float* __restrict__ x_leaf,   // [1024][512]
    const float* __restrict__ p_ws,     // [1024][64]
    const float* __restrict__ pw,       // [512][512][64]  ([o][i][l])
    const float* __restrict__ pb,       // [512][64]
    float* __restrict__ dst)            // parts [SK][1024][512] or out
{
  __shared__ __align__(16) float         xs[KI][256];    // 32 KB (transposed)
  __shared__ __align__(16) unsigned char bs8[2 * 16384]; // 2buf x 2sub x 8KB

  const int tid  = threadIdx.x;
  const int lane = tid & 63;
  const int wid  = tid >> 6;        // 0..3
  const int quad = lane >> 4;
  const int l15  = lane & 15;
  const int l7   = l15 & 7;

  const int bid = blockIdx.x;       // 512
  const int nt  = bid & 7;
  const int mt  = (bid >> 3) & 3;
  const int kc  = bid >> 5;         // 0..15

  const int row_m0 = mt * 256;
  const int o0     = nt * 64;
  const int i0     = kc * KI;
  const int wm     = wid * 64;      // 64 rows per wave

  // ---- stage x slab transposed [KI][256]: one row per thread ----
  {
    const float* src = x_leaf + (size_t)(row_m0 + tid) * IN_F + i0;
#pragma unroll
    for (int q = 0; q < 8; ++q) {
      float4 v = *(const float4*)(src + q * 4);
      xs[q * 4 + 0][tid] = v.x;
      xs[q * 4 + 1][tid] = v.y;
      xs[q * 4 + 2][tid] = v.z;
      xs[q * 4 + 3][tid] = v.w;
    }
  }

  // ---- p fragments, converted ONCE to f16 (reused all K) ----
  HF8 prh[4][2];
#pragma unroll
  for (int mi = 0; mi < 4; ++mi) {
    const int row = row_m0 + wm + mi * 16 + l15;
#pragma unroll
    for (int ks = 0; ks < 2; ++ks) {
      const f32x4* src = (const f32x4*)(p_ws + (size_t)row * NLEAF + ks * 32 + quad * 8);
      f32x4 lo = src[0], hi = src[1];
      prh[mi][ks].h2[0] = pkrtz(lo[0], lo[1]);
      prh[mi][ks].h2[1] = pkrtz(lo[2], lo[3]);
      prh[mi][ks].h2[2] = pkrtz(hi[0], hi[1]);
      prh[mi][ks].h2[3] = pkrtz(hi[2], hi[3]);
    }
  }

  // ---- B-load geometry: thread = (br = tid>>2 of 64 o-rows, seg = tid&3) ----
  const int br  = tid >> 2;
  const int seg = tid & 3;
  const float* bsrc0 = pw + ((size_t)(o0 + br) * IN_F + i0) * NLEAF + seg * 16;

  // swizzled LDS offsets (XOR touches byte bits 4-6 only; fields don't carry)
  const int wsw   = (br & 7) << 4;
  const int woff0 = br * 128 + ((seg * 32) ^ wsw);
  const int woff1 = br * 128 + ((seg * 32 + 16) ^ wsw);
  int coff[2];
#pragma unroll
  for (int ks = 0; ks < 2; ++ks)
    coff[ks] = (ks * 64 + quad * 16) ^ (l7 << 4);
  const int rbase = l15 * 128;

  f32x4 acc[4][4];
#pragma unroll
  for (int mi = 0; mi < 4; ++mi)
#pragma unroll
    for (int ni = 0; ni < 4; ++ni)
      acc[mi][ni] = (f32x4)(0.f);

  f32x4 rb[4][4];   // 4-slot register prefetch (tile T -> slot T&3)
  HF8 afA[2][4], afB[2][4];  // A fragments, ping-pong across i-steps

  // volatile asm loads: issue exactly here, never sink; "=&v" early-clobber
  // (R5 lesson: without it a dest tuple may alias the in-flight addr pair).
#define BLOAD(T, SLOT)                                                        \
  {                                                                           \
    const float* a_ = bsrc0 + (size_t)(T) * NLEAF;                            \
    asm volatile(                                                             \
        "global_load_dwordx4 %0, %4, off\n\t"                                 \
        "global_load_dwordx4 %1, %4, off offset:16\n\t"                       \
        "global_load_dwordx4 %2, %4, off offset:32\n\t"                       \
        "global_load_dwordx4 %3, %4, off offset:48"                           \
        : "=&v"(rb[SLOT][0]), "=&v"(rb[SLOT][1]),                             \
          "=&v"(rb[SLOT][2]), "=&v"(rb[SLOT][3])                              \
        : "v"(a_) : "memory");                                                \
  }

  // counted wait tied to the slot's regs. NO sched_barrier: all consumers
  // (pkrtz in BSTAGE) have true SSA deps on the "+v" outputs, so they can't
  // hoist; leaving the scheduler free lets stage VALU slide under MFMAs.
#define BWAIT_(SLOT, N)                                                       \
  asm volatile("s_waitcnt vmcnt(" #N ")"                                      \
               : "+v"(rb[SLOT][0]), "+v"(rb[SLOT][1]),                        \
                 "+v"(rb[SLOT][2]), "+v"(rb[SLOT][3])::"memory");
#define BWAIT(SLOT, N) BWAIT_(SLOT, N)

#define BSTAGE(SLOT, BUF, SUB)                                                \
  {                                                                           \
    HF8 c0_, c1_;                                                             \
    f32x4 a0_ = rb[SLOT][0], a1_ = rb[SLOT][1];                               \
    f32x4 a2_ = rb[SLOT][2], a3_ = rb[SLOT][3];                               \
    c0_.h2[0] = pkrtz(a0_[0], a0_[1]);                                        \
    c0_.h2[1] = pkrtz(a0_[2], a0_[3]);                                        \
    c0_.h2[2] = pkrtz(a1_[0], a1_[1]);                                        \
    c0_.h2[3] = pkrtz(a1_[2], a1_[3]);                                        \
    c1_.h2[0] = pkrtz(a2_[0], a2_[1]);                                        \
    c1_.h2[1] = pkrtz(a2_[2], a2_[3]);                                        \
    c1_.h2[2] = pkrtz(a3_[0], a3_[1]);                                        \
    c1_.h2[3] = pkrtz(a3_[2], a3_[3]);                                        \
    unsigned char* d_ = bs8 + (BUF) * 16384 + (SUB) * 8192;                   \
    *(uint4*)(d_ + woff0) = c0_.u;                                            \
    *(uint4*)(d_ + woff1) = c1_.u;                                            \
  }

  // own DS ops drained, then workgroup barrier — NO vmcnt drain: the pinned
  // global B-prefetch stays in flight across barriers.
#define BARRIER() asm volatile("s_waitcnt lgkmcnt(0)\n\ts_barrier" ::: "memory")

  // A-build for i-step IT into AF. Touches only xs (read-only all kernel)
  // and prh — independent of bs buffers and barriers.
#define PREP(IT, AF)                                                          \
  {                                                                           \
    float xvf[4];                                                             \
    _Float16 xh[4];                                                           \
    _Pragma("unroll")                                                         \
    for (int mi = 0; mi < 4; ++mi) xvf[mi] = xs[(IT)][wm + mi * 16 + l15];    \
    _Pragma("unroll")                                                         \
    for (int mi = 0; mi < 4; ++mi) xh[mi] = (_Float16)xvf[mi];                \
    _Pragma("unroll")                                                         \
    for (int ks = 0; ks < 2; ++ks) {                                          \
      _Pragma("unroll")                                                       \
      for (int mi = 0; mi < 4; ++mi) {                                        \
        f16x2 xp_; xp_[0] = xh[mi]; xp_[1] = xh[mi];                          \
        _Pragma("unroll")                                                     \
        for (int j = 0; j < 4; ++j) AF[ks][mi].h2[j] = prh[mi][ks].h2[j] * xp_; \
      }                                                                       \
    }                                                                         \
  }

  // MFMA cluster: 8 bfr ds_reads + 32 MFMA on prepared AF.
#define MFMAC(AF, BUF, SUB)                                                   \
  {                                                                           \
    const unsigned char* bsr_ = bs8 + (BUF) * 16384 + (SUB) * 8192;           \
    __builtin_amdgcn_s_setprio(1);                                            \
    _Pragma("unroll")                                                         \
    for (int ks = 0; ks < 2; ++ks) {                                          \
      _Pragma("unroll")                                                       \
      for (int ni = 0; ni < 4; ++ni) {                                        \
        h16x8 bfr = *(const h16x8*)(bsr_ + ni * 2048 + rbase + coff[ks]);     \
        _Pragma("unroll")                                                     \
        for (int mi = 0; mi < 4; ++mi)                                        \
          acc[mi][ni] = __builtin_amdgcn_mfma_f32_16x16x32_f16(               \
              AF[ks][mi].v, bfr, acc[mi][ni], 0, 0, 0);                       \
      }                                                                       \
    }                                                                         \
    __builtin_amdgcn_s_setprio(0);                                            \
  }

// Phase: invariant on entry: afA = af(IT0); bs[BUF] holds tiles IT0,IT0+1.
// PN: whether to prep IT0+2 (exit invariant afA = af(IT0+2)).
#define PHASE(IT0, BUF, SA, SB, WA, WB, DLA, DLB, PN)                         \
  {                                                                           \
    PREP((IT0) + 1, afB)                                                      \
    MFMAC(afA, BUF, 0)                                                        \
    BWAIT(SA, WA)                                                             \
    BSTAGE(SA, (BUF) ^ 1, 0)                                                  \
    if (DLA) { BLOAD((IT0) + 6, SA) }                                         \
    if (PN)  { PREP((IT0) + 2, afA) }                                         \
    MFMAC(afB, BUF, 1)                                                        \
    BWAIT(SB, WB)                                                             \
    BSTAGE(SB, (BUF) ^ 1, 1)                                                  \
    if (DLB) { BLOAD((IT0) + 7, SB) }                                         \
    BARRIER();                                                                \
  }

  // ---- prologue: tiles 0..3 issued; stage 0,1; issue 4,5; prep af(0) ----
  BLOAD(0, 0)
  BLOAD(1, 1)
  BLOAD(2, 2)
  BLOAD(3, 3)
  BWAIT(0, 12)
  BSTAGE(0, 0, 0)
  BWAIT(1, 8)
  BSTAGE(1, 0, 1)
  BLOAD(4, 0)
  BLOAD(5, 1)
  BARRIER();         // xs + bs[0] visible; tiles {2,3,4,5} in flight
  PREP(0, afA)

  // ---- steady phases (tiles 0..25; loads through tile 31) ----
  for (int pp = 0; pp < 24; pp += 8) {
    PHASE(pp + 0, 0, 2, 3, 12, 12, 1, 1, 1)
    PHASE(pp + 2, 1, 0, 1, 12, 12, 1, 1, 1)
    PHASE(pp + 4, 0, 2, 3, 12, 12, 1, 1, 1)
    PHASE(pp + 6, 1, 0, 1, 12, 12, 1, 1, 1)
  }
  PHASE(24, 0, 2, 3, 12, 12, 1, 1, 1)   // p12: loads tiles 30,31
  // ---- drain ----
  PHASE(26, 1, 0, 1, 12, 8, 0, 0, 1)    // p13: stage 28,29
  PHASE(28, 0, 2, 3, 4, 0, 0, 0, 1)     // p14: stage 30,31; preps 29,30
  // ---- final pair (bs buf 1 holds 30,31) ----
  PREP(31, afB)
  MFMAC(afA, 1, 0)                      // tile 30
  MFMAC(afB, 1, 1)                      // tile 31

#undef BLOAD
#undef BWAIT
#undef BWAIT_
#undef BSTAGE
#undef BARRIER
#undef PREP
#undef MFMAC
#undef PHASE

  // ---- pb fold: kc==0 blocks add p @ pb^T via one pseudo-i-step ----
  if (kc == 0) {
    // stage pb tile (rows o0..o0+63, all 64 l) into bs[0] sub0 — same
    // geometry as a pw i-tile. Safe: all buf-0 reads ended at p14's BARRIER.
    {
      const float* pbs = pb + (size_t)(o0 + br) * NLEAF + seg * 16;
      float4 a0_ = *(const float4*)(pbs);
      float4 a1_ = *(const float4*)(pbs + 4);
      float4 a2_ = *(const float4*)(pbs + 8);
      float4 a3_ = *(const float4*)(pbs + 12);
      HF8 c0_, c1_;
      c0_.h2[0] = pkrtz(a0_.x, a0_.y);
      c0_.h2[1] = pkrtz(a0_.z, a0_.w);
      c0_.h2[2] = pkrtz(a1_.x, a1_.y);
      c0_.h2[3] = pkrtz(a1_.z, a1_.w);
      c1_.h2[0] = pkrtz(a2_.x, a2_.y);
      c1_.h2[1] = pkrtz(a2_.z, a2_.w);
      c1_.h2[2] = pkrtz(a3_.x, a3_.y);
      c1_.h2[3] = pkrtz(a3_.z, a3_.w);
      *(uint4*)(bs8 + woff0) = c0_.u;
      *(uint4*)(bs8 + woff1) = c1_.u;
    }
    __syncthreads();
    const unsigned char* bsr_ = bs8;
#pragma unroll
    for (int ks = 0; ks < 2; ++ks) {
#pragma unroll
      for (int ni = 0; ni < 4; ++ni) {
        h16x8 bfr = *(const h16x8*)(bsr_ + ni * 2048 + rbase + coff[ks]);
#pragma unroll
        for (int mi = 0; mi < 4; ++mi)
          acc[mi][ni] = __builtin_amdgcn_mfma_f32_16x16x32_f16(
              prh[mi][ks].v, bfr, acc[mi][ni], 0, 0, 0);
      }
    }
  }

  // ---- epilogue ----
#pragma unroll
  for (int mi = 0; mi < 4; ++mi) {
#pragma unroll
    for (int ni = 0; ni < 4; ++ni) {
      int row = row_m0 + wm + mi * 16 + quad * 4;
      int col = o0 + ni * 16 + l15;
      if (ATOMIC) {
        float* o = dst + (size_t)row * OUT_F + col;
        atomicAdd(o,             acc[mi][ni][0]);
        atomicAdd(o + OUT_F,     acc[mi][ni][1]);
        atomicAdd(o + 2 * OUT_F, acc[mi][ni][2]);
        atomicAdd(o + 3 * OUT_F, acc[mi][ni][3]);
      } else {
        float* o = dst + ((size_t)kc << 19) + (size_t)row * OUT_F + col;
        o[0]         = acc[mi][ni][0];
        o[OUT_F]     = acc[mi][ni][1];
        o[2 * OUT_F] = acc[mi][ni][2];
        o[3 * OUT_F] = acc[mi][ni][3];
      }
    }
  }
}

// ---------------------------------------------------------------------------
// Kernel 3 (slimmed): out = sum_kc parts[kc]  (pb handled in k_fused).
// nparts==0 -> zero-init for the atomic fallback.
// ---------------------------------------------------------------------------
__global__ __launch_bounds__(256, 8) void k_reduce(
    const float* __restrict__ parts, float* __restrict__ out, int nparts)
{
  const int idx = blockIdx.x * 256 + threadIdx.x;   // f32x4 index, 131072 total
  f32x4 a = (f32x4)(0.f);
#pragma unroll 8
  for (int k = 0; k < nparts; ++k)
    a += ((const f32x4*)(parts + ((size_t)k << 19)))[idx];
  ((f32x4*)out)[idx] = a;
}

// ---------------------------------------------------------------------------
extern "C" void kernel_launch(void* const* d_in, const int* in_sizes, int n_in,
                              void* d_out, int out_size, void* d_ws, size_t ws_size,
                              hipStream_t stream) {
  const float* xg = (const float*)d_in[0];   // x_gating [1024][512]
  const float* xl = (const float*)d_in[1];   // x_leaf   [1024][512]
  const float* gw = (const float*)d_in[2];   // [512][63]
  const float* gb = (const float*)d_in[3];   // [63]
  const float* pw = (const float*)d_in[4];   // [512][512][64]
  const float* pb = (const float*)d_in[5];   // [512][64]
  float* out = (float*)d_out;

  // ws: p fp32 (256 KB) | parts fp32 [SK][1024][512] (32 MB)
  const size_t P_BYTES = (size_t)B_SZ * NLEAF * 4;
  const size_t SLICE   = (size_t)B_SZ * OUT_F * 4;

  float* p_ws  = (float*)d_ws;
  float* parts = (float*)((char*)d_ws + P_BYTES);

  k_leafprobs<<<dim3(B_SZ), dim3(512), 0, stream>>>(xg, gw, gb, p_ws);

  if (ws_size >= P_BYTES + SK * SLICE) {
    k_fused<false><<<dim3(512), dim3(256), 0, stream>>>(xl, p_ws, pw, pb, parts);
    k_reduce<<<dim3(512), dim3(256), 0, stream>>>(parts, out, SK);
  } else {
    k_reduce<<<dim3(512), dim3(256), 0, stream>>>(parts, out, 0);
    k_fused<true><<<dim3(512), dim3(256), 0, stream>>>(xl, p_ws, pw, pb, out);
  }
}